// Round 2
// baseline (209.487 us; speedup 1.0000x reference)
//
#include <hip/hip_runtime.h>
#include <math.h>

// AttentionAggregator: out[n] = sum_k softmax_k(feats[n,k,:]·w) * feats[n,k,:]
// feats[n,k,:] = embed_table[neigh_idx[n,k], :]
// N=100000, K=10, VOCAB=200000, D=128, all fp32.
//
// One 64-lane wave per node, split as two 32-lane halves.
// Pair j: lane (half,sub) loads row 2j+half, dims [4*sub, 4*sub+4) as float4.
//   -> one dwordx4 wave-load fetches TWO full 512B rows (5 loads total vs 10)
//   -> dot-product butterfly is 5 levels within each 32-half (both rows of a
//      pair reduce in the same shuffle instructions) + 1 cross-half swap
// Fragments stay in registers (f[5] x float4 = 20 VGPRs); softmax over K=10
// is computed redundantly per lane — zero LDS.

#define KNEIGH 10
#define NPAIR  5
#define DIM    128

__global__ __launch_bounds__(256) void attn_agg_kernel(
    const float* __restrict__ table,
    const float* __restrict__ attn_w,
    const int*   __restrict__ idx,
    float*       __restrict__ out,
    int n_nodes)
{
    const int gtid = blockIdx.x * blockDim.x + threadIdx.x;
    const int node = gtid >> 6;                 // one wave per node
    if (node >= n_nodes) return;
    const int lane = threadIdx.x & 63;
    const int half = lane >> 5;                 // which row of the pair
    const int sub  = lane & 31;                 // dim-chunk within the row

    // attention weights: 4 floats per lane (L1-broadcast)
    const float4 w4 = *(const float4*)(attn_w + sub * 4);

    // lanes 0..K-1 hold the K neighbor indices
    int my_idx = 0;
    if (lane < KNEIGH) my_idx = idx[node * KNEIGH + lane];

    // broadcast the row id each lane needs (row 2j+half)
    int id[NPAIR];
    #pragma unroll
    for (int j = 0; j < NPAIR; ++j)
        id[j] = __shfl(my_idx, 2 * j + half, 64);

    // issue all 5 gathers back-to-back (max outstanding loads)
    float4 f[NPAIR];
    #pragma unroll
    for (int j = 0; j < NPAIR; ++j)
        f[j] = *(const float4*)(table + (size_t)id[j] * DIM + sub * 4);

    // scores: per-lane partial dot, 5-level butterfly within each 32-half
    // (sums both rows of the pair simultaneously), then cross-half swap
    float s[KNEIGH];
    #pragma unroll
    for (int j = 0; j < NPAIR; ++j) {
        float p = f[j].x * w4.x + f[j].y * w4.y + f[j].z * w4.z + f[j].w * w4.w;
        #pragma unroll
        for (int off = 16; off >= 1; off >>= 1)
            p += __shfl_xor(p, off, 64);        // stays within 32-lane half
        const float q = __shfl_xor(p, 32, 64);  // other half's row score
        s[2 * j]     = half ? q : p;            // score of row 2j
        s[2 * j + 1] = half ? p : q;            // score of row 2j+1
    }

    // softmax over K=10 (redundant per lane — trivially cheap)
    float m = s[0];
    #pragma unroll
    for (int k = 1; k < KNEIGH; ++k) m = fmaxf(m, s[k]);
    float denom = 0.f;
    #pragma unroll
    for (int k = 0; k < KNEIGH; ++k) { s[k] = __expf(s[k] - m); denom += s[k]; }
    const float inv = 1.0f / denom;

    // weighted sum: each lane accumulates its 5 rows x 4 dims
    float4 acc = make_float4(0.f, 0.f, 0.f, 0.f);
    #pragma unroll
    for (int j = 0; j < NPAIR; ++j) {
        const float wk = (half ? s[2 * j + 1] : s[2 * j]) * inv;
        acc.x = fmaf(wk, f[j].x, acc.x);
        acc.y = fmaf(wk, f[j].y, acc.y);
        acc.z = fmaf(wk, f[j].z, acc.z);
        acc.w = fmaf(wk, f[j].w, acc.w);
    }

    // combine the two halves (even rows + odd rows), lower half stores
    acc.x += __shfl_xor(acc.x, 32, 64);
    acc.y += __shfl_xor(acc.y, 32, 64);
    acc.z += __shfl_xor(acc.z, 32, 64);
    acc.w += __shfl_xor(acc.w, 32, 64);

    if (half == 0)
        *(float4*)(out + (size_t)node * DIM + sub * 4) = acc;
}

extern "C" void kernel_launch(void* const* d_in, const int* in_sizes, int n_in,
                              void* d_out, int out_size, void* d_ws, size_t ws_size,
                              hipStream_t stream) {
    const float* table  = (const float*)d_in[0];   // [VOCAB, D] fp32
    const float* attn_w = (const float*)d_in[1];   // [D] fp32
    const int*   idx    = (const int*)d_in[2];     // [N, K] int32
    float*       out    = (float*)d_out;           // [N, D] fp32

    const int n_nodes = in_sizes[2] / KNEIGH;
    const int waves_per_block = 4;                 // 256 threads
    const int blocks = (n_nodes + waves_per_block - 1) / waves_per_block;
    attn_agg_kernel<<<blocks, 256, 0, stream>>>(table, attn_w, idx, out, n_nodes);
}